// Round 13
// baseline (325.264 us; speedup 1.0000x reference)
//
#include <hip/hip_runtime.h>
#include <hip/hip_cooperative_groups.h>
#include <hip/hip_bf16.h>
#include <hip/hip_fp8.h>
#include <stdint.h>

namespace cg = cooperative_groups;

#define Nn 8192
#define TWO_N 16384
#define INV_TAU 2.0f
#define EXP2_SCALE 2.885390081777927f   /* INV_TAU * log2(e) */

typedef unsigned short u16;
typedef unsigned char u8;
typedef __bf16 bf16x8 __attribute__((ext_vector_type(8)));
typedef float f32x4 __attribute__((ext_vector_type(4)));
typedef int i32x8 __attribute__((ext_vector_type(8)));

typedef const __attribute__((address_space(1))) void* gas_ptr;
typedef __attribute__((address_space(3))) void* las_ptr;

__device__ __forceinline__ void async_copy16(const void* g, void* l) {
  __builtin_amdgcn_global_load_lds((gas_ptr)g, (las_ptr)l, 16, 0, 0);
}

// v_exp_f32: D = 2^S0 (hardware transcendental)
__device__ __forceinline__ float hw_exp2(float x) {
  return __builtin_amdgcn_exp2f(x);
}

// ============================ phase bodies ===================================
// All bodies are the measured-best R6 code, factored so the fused cooperative
// kernel and the (fallback) standalone kernels share one implementation.

// ---- fused MLP + normalize + fp8 emit (one 64-row tile; R6 body) ----
// smem layout: sZ = smem[0:8K), sW = smem[8K:40K), sH = smem[40K:72K)
__device__ __forceinline__
void mlp_body(int bx, u8* smem,
              const float* __restrict__ z1, const float* __restrict__ z2,
              const __bf16* __restrict__ Wb, const float* __restrict__ b1,
              const float* __restrict__ b2, u8* __restrict__ Mf8,
              float* __restrict__ snorm, float* __restrict__ rsum) {
  __bf16* sZ = (__bf16*)(smem);
  __bf16* sW = (__bf16*)(smem + 8192);
  __bf16* sH = (__bf16*)(smem + 40960);
  const int i0 = bx * 64;
  const float* Zsrc = (bx < 128) ? (z1 + (size_t)i0 * 256)
                                 : (z2 + (size_t)(i0 - Nn) * 256);
  const int t = threadIdx.x;
  const int lane = t & 63, wave = t >> 6;
  const int wn = wave * 64;
  const int fr = lane >> 4, fc = lane & 15;
  const int sw = fc & 7;

  const __bf16* Wb1 = Wb;
  const __bf16* Wb2 = Wb + 65536;

  if (t < 64) rsum[i0 + t] = 0.f;

  f32x4 acc[4][4];
#pragma unroll
  for (int a = 0; a < 4; a++)
#pragma unroll
    for (int b = 0; b < 4; b++) acc[a][b] = (f32x4){0.f, 0.f, 0.f, 0.f};

  // ---- layer 1 ----
  for (int k0 = 0; k0 < 256; k0 += 64) {
    __syncthreads();
#pragma unroll
    for (int it = 0; it < 8; ++it) {               // W1: async DMA
      int c = t + 256 * it;
      int row = c >> 3, g = (c & 7) ^ (row & 7);
      async_copy16(Wb1 + (size_t)row * 256 + k0 + g * 8, (void*)&sW[c * 8]);
    }
#pragma unroll
    for (int it = 0; it < 2; ++it) {               // Z: convert
      int c = t + 256 * it;
      int row = c >> 3, g = (c & 7) ^ (row & 7);
      const float* s = Zsrc + (size_t)row * 256 + k0 + g * 8;
      float4 a0 = *(const float4*)s, a1 = *(const float4*)(s + 4);
      bf16x8 v = {(__bf16)a0.x, (__bf16)a0.y, (__bf16)a0.z, (__bf16)a0.w,
                  (__bf16)a1.x, (__bf16)a1.y, (__bf16)a1.z, (__bf16)a1.w};
      *(bf16x8*)&sZ[c * 8] = v;
    }
    __syncthreads();
#pragma unroll
    for (int ks = 0; ks < 2; ++ks) {
      bf16x8 af[4], bfr[4];
#pragma unroll
      for (int mi = 0; mi < 4; mi++)
        af[mi] = *(const bf16x8*)&sZ[(mi * 16 + fc) * 64 + (((ks * 4 + fr) ^ sw) * 8)];
#pragma unroll
      for (int ni = 0; ni < 4; ni++)
        bfr[ni] = *(const bf16x8*)&sW[(wn + ni * 16 + fc) * 64 + (((ks * 4 + fr) ^ sw) * 8)];
#pragma unroll
      for (int mi = 0; mi < 4; mi++)
#pragma unroll
        for (int ni = 0; ni < 4; ni++)
          acc[mi][ni] = __builtin_amdgcn_mfma_f32_16x16x32_bf16(af[mi], bfr[ni], acc[mi][ni], 0, 0, 0);
    }
  }

  // layer-1 epilogue: bias + elu -> bf16 into sH
  {
    float bv[4];
#pragma unroll
    for (int ni = 0; ni < 4; ni++) bv[ni] = b1[wn + ni * 16 + fc];
#pragma unroll
    for (int mi = 0; mi < 4; mi++)
#pragma unroll
      for (int ni = 0; ni < 4; ni++) {
        int col = wn + ni * 16 + fc;
        int gc = col >> 3;
#pragma unroll
        for (int r = 0; r < 4; r++) {
          int row = mi * 16 + fr * 4 + r;
          float v = acc[mi][ni][r] + bv[ni];
          v = v > 0.f ? v : (__expf(v) - 1.f);
          int pos = (gc & 24) | ((gc & 7) ^ (row & 7));
          sH[row * 256 + pos * 8 + (col & 7)] = (__bf16)v;
          acc[mi][ni][r] = 0.f;
        }
      }
  }

  // ---- layer 2 ----
  for (int k0 = 0; k0 < 256; k0 += 64) {
    __syncthreads();
#pragma unroll
    for (int it = 0; it < 8; ++it) {               // W2: async DMA
      int c = t + 256 * it;
      int row = c >> 3, g = (c & 7) ^ (row & 7);
      async_copy16(Wb2 + (size_t)row * 256 + k0 + g * 8, (void*)&sW[c * 8]);
    }
    __syncthreads();
    const int kgb = k0 >> 3;
#pragma unroll
    for (int ks = 0; ks < 2; ++ks) {
      bf16x8 af[4], bfr[4];
#pragma unroll
      for (int mi = 0; mi < 4; mi++)
        af[mi] = *(const bf16x8*)&sH[(mi * 16 + fc) * 256 + (kgb + (((ks * 4 + fr) ^ sw))) * 8];
#pragma unroll
      for (int ni = 0; ni < 4; ni++)
        bfr[ni] = *(const bf16x8*)&sW[(wn + ni * 16 + fc) * 64 + (((ks * 4 + fr) ^ sw) * 8)];
#pragma unroll
      for (int mi = 0; mi < 4; mi++)
#pragma unroll
        for (int ni = 0; ni < 4; ni++)
          acc[mi][ni] = __builtin_amdgcn_mfma_f32_16x16x32_bf16(af[mi], bfr[ni], acc[mi][ni], 0, 0, 0);
    }
  }

  // ---- epilogue: bias, cross-wave row-norm, fp8 emit, snorm ----
  float bv[4];
#pragma unroll
  for (int ni = 0; ni < 4; ni++) bv[ni] = b2[wn + ni * 16 + fc];

  __syncthreads();                 // sZ dead; reuse as reduce scratch
  float* red = (float*)sZ;         // [64 rows][4 waves]
  float* red2 = red + 256;

#pragma unroll
  for (int mi = 0; mi < 4; mi++) {
    float ssq[4] = {0.f, 0.f, 0.f, 0.f};
#pragma unroll
    for (int ni = 0; ni < 4; ni++)
#pragma unroll
      for (int r = 0; r < 4; r++) {
        float v = acc[mi][ni][r] + bv[ni];
        acc[mi][ni][r] = v;
        ssq[r] += v * v;
      }
#pragma unroll
    for (int r = 0; r < 4; r++) {
      float v = ssq[r];
#pragma unroll
      for (int off = 1; off < 16; off <<= 1) v += __shfl_xor(v, off, 16);
      if (fc == 0) red[(mi * 16 + fr * 4 + r) * 4 + wave] = v;
    }
  }
  __syncthreads();

#pragma unroll
  for (int mi = 0; mi < 4; mi++) {
    float ssq2[4] = {0.f, 0.f, 0.f, 0.f};
#pragma unroll
    for (int r = 0; r < 4; r++) {
      int row = mi * 16 + fr * 4 + r;
      float ss = red[row * 4] + red[row * 4 + 1] + red[row * 4 + 2] + red[row * 4 + 3];
      float rn = 1.f / fmaxf(sqrtf(ss), 1e-12f);
#pragma unroll
      for (int ni = 0; ni < 4; ni++) {
        float v = acc[mi][ni][r] * rn;
        __hip_fp8_e4m3 q(v);
        Mf8[(size_t)(i0 + row) * 256 + wn + ni * 16 + fc] = q.__x;
        float fv = (float)q;
        ssq2[r] += fv * fv;
      }
    }
#pragma unroll
    for (int r = 0; r < 4; r++) {
      float v = ssq2[r];
#pragma unroll
      for (int off = 1; off < 16; off <<= 1) v += __shfl_xor(v, off, 16);
      if (fc == 0) red2[(mi * 16 + fr * 4 + r) * 4 + wave] = v;
    }
  }
  __syncthreads();
  if (t < 64)
    snorm[i0 + t] = red2[t * 4] + red2[t * 4 + 1] + red2[t * 4 + 2] + red2[t * 4 + 3];
}

// ---- symmetric Gram strip (R6 body; one strip of <=4 tiles) ----
// smem layout: sB0 = smem[0:32K), sB1 = smem[32K:64K)
__device__ __forceinline__
void gram_body(int s, u8* smem, const u8* __restrict__ Mf8,
               float* __restrict__ rsum) {
  u8* sB0 = smem;
  u8* sB1 = smem + 32768;
  const int t = threadIdx.x;
  const int lane = t & 63, wave = t >> 6;
  const int wm = (wave >> 1) * 64, wn = (wave & 1) * 64;
  const int fr = lane >> 4, fc = lane & 15;

  // ---- strip mapping (band closed form), long strips first ----
  int f = 2111 - s;
  int b = 0;
  while (f >= 2 * (b + 1) * (b + 2)) ++b;
  int rem = f - 2 * b * (b + 1);
  int r = rem / (b + 1);
  int q = rem - r * (b + 1);
  int k = 4 * b + 1 + r;
  const int i_t = 128 - k;
  const int jt0 = i_t + 4 * q;
  const int L = min(4, k - 4 * q);
  const int i0 = i_t * 128;

  __syncthreads();   // persistent reuse: prior strip's sB reads all done

  // stage B(tile 0) into buffer 0
  {
    const u8* Bg = Mf8 + (size_t)jt0 * 128 * 256;
#pragma unroll
    for (int it = 0; it < 8; ++it) {
      int c = t + 256 * it;
      int row = c >> 4, slot = c & 15;
      int g = slot ^ (row & 15);
      async_copy16(Bg + (size_t)row * 256 + g * 16, (void*)&sB0[c * 16]);
    }
  }

  // gather A fragments into registers (L2/L3-resident; once per strip)
  i32x8 afr[4][2];
  {
    const u8* Ag = Mf8 + (size_t)i0 * 256;
#pragma unroll
    for (int mi = 0; mi < 4; ++mi) {
      const u8* rp = Ag + (size_t)(wm + mi * 16 + fc) * 256 + fr * 32;
#pragma unroll
      for (int kb = 0; kb < 2; ++kb) {
        int4 lo = *(const int4*)(rp + kb * 128);
        int4 hi = *(const int4*)(rp + kb * 128 + 16);
        afr[mi][kb] = (i32x8){lo.x, lo.y, lo.z, lo.w, hi.x, hi.y, hi.z, hi.w};
      }
    }
  }

  float rowacc[4][4];
  float colps[4][4];               // [tile][ni], flushed at strip end
#pragma unroll
  for (int a = 0; a < 4; a++)
#pragma unroll
    for (int rr = 0; rr < 4; rr++) { rowacc[a][rr] = 0.f; colps[a][rr] = 0.f; }

#pragma unroll
  for (int jt = 0; jt < 4; ++jt) {
    if (jt < L) {                  // block-uniform guard (L uniform)
      const int j_t = jt0 + jt;
      const u8* sB = (jt & 1) ? sB1 : sB0;

      __syncthreads();   // drains B(jt) staging (issued >=1 tile ago; landed)

      if (jt + 1 < L) {  // prefetch B(jt+1) behind the barrier
        const u8* Bg = Mf8 + (size_t)(j_t + 1) * 128 * 256;
        u8* dst = ((jt + 1) & 1) ? sB1 : sB0;
#pragma unroll
        for (int it = 0; it < 8; ++it) {
          int c = t + 256 * it;
          int row = c >> 4, slot = c & 15;
          int g = slot ^ (row & 15);
          async_copy16(Bg + (size_t)row * 256 + g * 16, (void*)&dst[c * 16]);
        }
      }

      f32x4 acc[4][4];
#pragma unroll
      for (int a = 0; a < 4; a++)
#pragma unroll
        for (int bb = 0; bb < 4; bb++) acc[a][bb] = (f32x4){0.f, 0.f, 0.f, 0.f};

#pragma unroll
      for (int kb = 0; kb < 2; ++kb) {
        i32x8 bfrag[4];
#pragma unroll
        for (int ni = 0; ni < 4; ++ni) {
          const u8* base = sB + (wn + ni * 16 + fc) * 256;
          int g0 = kb * 8 + fr * 2;
          int4 lo = *(const int4*)(base + ((g0 ^ fc) * 16));
          int4 hi = *(const int4*)(base + (((g0 + 1) ^ fc) * 16));
          bfrag[ni] = (i32x8){lo.x, lo.y, lo.z, lo.w, hi.x, hi.y, hi.z, hi.w};
        }
#pragma unroll
        for (int mi = 0; mi < 4; mi++)
#pragma unroll
          for (int ni = 0; ni < 4; ni++)
            acc[mi][ni] = __builtin_amdgcn_mfma_scale_f32_16x16x128_f8f6f4(
                afr[mi][kb], bfrag[ni], acc[mi][ni], 0, 0, 0, 0x7F, 0, 0x7F);
      }

      // tile epilogue: exp2-folded, register-only accumulation
#pragma unroll
      for (int mi = 0; mi < 4; mi++) {
#pragma unroll
        for (int ni = 0; ni < 4; ni++) {
          float e0 = hw_exp2(acc[mi][ni][0] * EXP2_SCALE);
          float e1 = hw_exp2(acc[mi][ni][1] * EXP2_SCALE);
          float e2 = hw_exp2(acc[mi][ni][2] * EXP2_SCALE);
          float e3 = hw_exp2(acc[mi][ni][3] * EXP2_SCALE);
          rowacc[mi][0] += e0; rowacc[mi][1] += e1;
          rowacc[mi][2] += e2; rowacc[mi][3] += e3;
          colps[jt][ni] += e0 + e1 + e2 + e3;
        }
      }
    }
  }

  // ---- strip-end flush: all global atomics live here ----
#pragma unroll
  for (int jt = 0; jt < 4; ++jt) {
    if (jt < L) {
      const int j_t = jt0 + jt;
      if (j_t != i_t) {
        const int j0 = j_t * 128;
#pragma unroll
        for (int ni = 0; ni < 4; ni++) {
          float v = colps[jt][ni];
          v += __shfl_xor(v, 16, 64);
          v += __shfl_xor(v, 32, 64);
          if (fr == 0) atomicAdd(&rsum[j0 + wn + ni * 16 + fc], v);
        }
      }
    }
  }

#pragma unroll
  for (int mi = 0; mi < 4; mi++) {
#pragma unroll
    for (int rr = 0; rr < 4; rr++) {
      float v = rowacc[mi][rr];
#pragma unroll
      for (int off = 1; off < 16; off <<= 1) v += __shfl_xor(v, off, 16);
      rowacc[mi][rr] = v;
    }
  }
  if (fc == 0) {
#pragma unroll
    for (int mi = 0; mi < 4; mi++) {
      int rbase = i0 + wm + mi * 16 + fr * 4;
      atomicAdd(&rsum[rbase + 0], rowacc[mi][0]);
      atomicAdd(&rsum[rbase + 1], rowacc[mi][1]);
      atomicAdd(&rsum[rbase + 2], rowacc[mi][2]);
      atomicAdd(&rsum[rbase + 3], rowacc[mi][3]);
    }
  }
}

// ---- final loss for one row i (wave-cooperative) ----
__device__ __forceinline__
void final_body(int i, int lane, const u8* __restrict__ Mf8,
                const float* __restrict__ rsum, const float* __restrict__ snorm,
                float* __restrict__ out) {
  unsigned int ua = ((const unsigned int*)(Mf8 + (size_t)i * 256))[lane];
  unsigned int ub = ((const unsigned int*)(Mf8 + (size_t)(Nn + i) * 256))[lane];
  float d = 0.f;
#pragma unroll
  for (int e = 0; e < 4; ++e) {
    __hip_fp8_e4m3 qa, qb;
    qa.__x = (ua >> (8 * e)) & 0xFF;
    qb.__x = (ub >> (8 * e)) & 0xFF;
    d += (float)qa * (float)qb;
  }
#pragma unroll
  for (int off = 32; off; off >>= 1) d += __shfl_xor(d, off, 64);
  if (lane == 0) {
    float den1 = rsum[i] - __expf(snorm[i] * INV_TAU);
    float den2 = rsum[Nn + i] - __expf(snorm[Nn + i] * INV_TAU);
    out[i] = 0.5f * (logf(den1) + logf(den2)) - d * INV_TAU;
  }
}

// ============================ fused cooperative kernel =======================
// 512 blocks x 256 thr, ALL co-resident (2 blocks/CU: 72KB LDS x2 = 144 <=
// 160KB, VGPR capped 124 by launch_bounds(256,2)). Replaces 4 stream launches
// (~17 us each, measured R9: +1 launch = +17.2 us) with 1 launch + 3
// grid.sync()s (~2-3 us each).
__global__ __launch_bounds__(256, 2)
void fused_all(const float* __restrict__ z1, const float* __restrict__ z2,
               const float* __restrict__ W1, const float* __restrict__ b1,
               const float* __restrict__ W2, const float* __restrict__ b2,
               u8* __restrict__ Mf8, float* __restrict__ rsum,
               float* __restrict__ snorm, __bf16* __restrict__ Wb,
               float* __restrict__ out) {
  __shared__ __align__(16) u8 smem[73728];
  cg::grid_group grid = cg::this_grid();

  // phase 0: W f32 -> bf16 (131072 elems, 1/thread, coalesced)
  {
    int gi = blockIdx.x * 256 + threadIdx.x;
    float v = (gi < 65536) ? W1[gi] : W2[gi - 65536];
    Wb[gi] = (__bf16)v;
  }
  grid.sync();

  // phase 1: MLP (blocks 0..255 -> 1 working block/CU, as the R6 launch)
  if (blockIdx.x < 256)
    mlp_body(blockIdx.x, smem, z1, z2, Wb, b1, b2, Mf8, snorm, rsum);
  grid.sync();

  // phase 2: gram, persistent strips (long strips first across rounds)
  for (int s = blockIdx.x; s < 2112; s += 512)
    gram_body(s, smem, Mf8, rsum);
  grid.sync();

  // phase 3: final loss, 16 rows/block (4 rows/wave)
  {
    int wave = threadIdx.x >> 6, lane = threadIdx.x & 63;
#pragma unroll
    for (int rr = 0; rr < 4; ++rr)
      final_body(blockIdx.x * 16 + wave * 4 + rr, lane, Mf8, rsum, snorm, out);
  }
}

// ============================ fallback kernels (R6 path) =====================
__global__ __launch_bounds__(256)
void wcvt(const float* __restrict__ W1, const float* __restrict__ W2,
          __bf16* __restrict__ Wb) {
  int i = (blockIdx.x * 256 + threadIdx.x) * 8;
  const float* s = (i < 65536) ? (W1 + i) : (W2 + (i - 65536));
  float4 a0 = *(const float4*)s, a1 = *(const float4*)(s + 4);
  bf16x8 v = {(__bf16)a0.x, (__bf16)a0.y, (__bf16)a0.z, (__bf16)a0.w,
              (__bf16)a1.x, (__bf16)a1.y, (__bf16)a1.z, (__bf16)a1.w};
  *(bf16x8*)&Wb[i] = v;
}

__global__ __launch_bounds__(256)
void mlp_norm(const float* __restrict__ z1, const float* __restrict__ z2,
              const __bf16* __restrict__ Wb, const float* __restrict__ b1,
              const float* __restrict__ b2, u8* __restrict__ Mf8,
              float* __restrict__ snorm, float* __restrict__ rsum) {
  __shared__ __align__(16) u8 smem[73728];
  mlp_body(blockIdx.x, smem, z1, z2, Wb, b1, b2, Mf8, snorm, rsum);
}

__global__ __launch_bounds__(256, 2)
void gram_sym(const u8* __restrict__ Mf8, float* __restrict__ rsum) {
  __shared__ __align__(16) u8 smem[65536];
  gram_body(blockIdx.x, smem, Mf8, rsum);
}

__global__ void final_loss(const u8* __restrict__ Mf8, const float* __restrict__ rsum,
                           const float* __restrict__ snorm, float* __restrict__ out) {
  int i = blockIdx.x * 4 + (threadIdx.x >> 6);
  final_body(i, threadIdx.x & 63, Mf8, rsum, snorm, out);
}

// ============================ launcher =======================================
extern "C" void kernel_launch(void* const* d_in, const int* in_sizes, int n_in,
                              void* d_out, int out_size, void* d_ws, size_t ws_size,
                              hipStream_t stream) {
  const float* z1 = (const float*)d_in[0];
  const float* z2 = (const float*)d_in[1];
  const float* W1 = (const float*)d_in[2];
  const float* b1 = (const float*)d_in[3];
  const float* W2 = (const float*)d_in[4];
  const float* b2 = (const float*)d_in[5];
  float* out = (float*)d_out;

  char* ws = (char*)d_ws;
  u8*     Mf8   = (u8*)(ws);                           // 4 MB
  float*  rsum  = (float*)(ws + (4u << 20));           // 64 KB
  float*  snorm = (float*)(ws + (4u << 20) + 65536);   // 64 KB
  __bf16* Wb    = (__bf16*)(ws + (4u << 20) + 131072); // 256 KB (bf16 W1|W2)

  void* args[] = {(void*)&z1, (void*)&z2, (void*)&W1, (void*)&b1,
                  (void*)&W2, (void*)&b2, (void*)&Mf8, (void*)&rsum,
                  (void*)&snorm, (void*)&Wb, (void*)&out};
  hipError_t err = hipLaunchCooperativeKernel((const void*)fused_all,
                                              dim3(512), dim3(256),
                                              args, 0, stream);
  if (err != hipSuccess) {
    // fallback: proven R6 4-launch path
    wcvt<<<64, 256, 0, stream>>>(W1, W2, Wb);
    mlp_norm<<<256, 256, 0, stream>>>(z1, z2, Wb, b1, b2, Mf8, snorm, rsum);
    gram_sym<<<2112, 256, 0, stream>>>(Mf8, rsum);
    final_loss<<<Nn / 4, 256, 0, stream>>>(Mf8, rsum, snorm, out);
  }
}

// Round 14
// 204.847 us; speedup vs baseline: 1.5878x; 1.5878x over previous
//
#include <hip/hip_runtime.h>
#include <hip/hip_bf16.h>
#include <hip/hip_fp8.h>
#include <stdint.h>

#define Nn 8192
#define TWO_N 16384
#define INV_TAU 2.0f
#define EXP2_SCALE 2.885390081777927f   /* INV_TAU * log2(e) */

typedef unsigned short u16;
typedef unsigned char u8;
typedef __bf16 bf16x8 __attribute__((ext_vector_type(8)));
typedef float f32x4 __attribute__((ext_vector_type(4)));
typedef int i32x8 __attribute__((ext_vector_type(8)));

typedef const __attribute__((address_space(1))) void* gas_ptr;
typedef __attribute__((address_space(3))) void* las_ptr;

__device__ __forceinline__ void async_copy16(const void* g, void* l) {
  __builtin_amdgcn_global_load_lds((gas_ptr)g, (las_ptr)l, 16, 0, 0);
}

// v_exp_f32: D = 2^S0 (hardware transcendental)
__device__ __forceinline__ float hw_exp2(float x) {
  return __builtin_amdgcn_exp2f(x);
}

// ---------------- W f32 -> bf16 pre-convert (once, ~256 KB out) -------------
__global__ __launch_bounds__(256)
void wcvt(const float* __restrict__ W1, const float* __restrict__ W2,
          __bf16* __restrict__ Wb) {
  int i = (blockIdx.x * 256 + threadIdx.x) * 8;
  const float* s = (i < 65536) ? (W1 + i) : (W2 + (i - 65536));
  float4 a0 = *(const float4*)s, a1 = *(const float4*)(s + 4);
  bf16x8 v = {(__bf16)a0.x, (__bf16)a0.y, (__bf16)a0.z, (__bf16)a0.w,
              (__bf16)a1.x, (__bf16)a1.y, (__bf16)a1.z, (__bf16)a1.w};
  *(bf16x8*)&Wb[i] = v;
}

// ---------------- fused MLP + normalize + fp8 emit ---------------------------
// (round-6 version verbatim -- best measured; ~6 us per closed accounting)
__global__ __launch_bounds__(256)
void mlp_norm(const float* __restrict__ z1, const float* __restrict__ z2,
              const __bf16* __restrict__ Wb, const float* __restrict__ b1,
              const float* __restrict__ b2,
              u8* __restrict__ Mf8, float* __restrict__ snorm,
              float* __restrict__ rsum) {
  __shared__ __bf16 sZ[64 * 64];    // 8 KB  (layer1 A; reduce scratch later)
  __shared__ __bf16 sW[256 * 64];   // 32 KB (W chunk, both layers)
  __shared__ __bf16 sH[64 * 256];   // 32 KB (H1, full K for layer 2)
  const int bx = blockIdx.x;
  const int i0 = bx * 64;
  const float* Zsrc = (bx < 128) ? (z1 + (size_t)i0 * 256)
                                 : (z2 + (size_t)(i0 - Nn) * 256);
  const int t = threadIdx.x;
  const int lane = t & 63, wave = t >> 6;
  const int wn = wave * 64;
  const int fr = lane >> 4, fc = lane & 15;
  const int sw = fc & 7;

  const __bf16* Wb1 = Wb;
  const __bf16* Wb2 = Wb + 65536;

  if (t < 64) rsum[i0 + t] = 0.f;

  f32x4 acc[4][4];
#pragma unroll
  for (int a = 0; a < 4; a++)
#pragma unroll
    for (int b = 0; b < 4; b++) acc[a][b] = (f32x4){0.f, 0.f, 0.f, 0.f};

  // ---- layer 1 ----
  for (int k0 = 0; k0 < 256; k0 += 64) {
    __syncthreads();
#pragma unroll
    for (int it = 0; it < 8; ++it) {               // W1: 2048 granules, async DMA
      int c = t + 256 * it;
      int row = c >> 3, g = (c & 7) ^ (row & 7);
      async_copy16(Wb1 + (size_t)row * 256 + k0 + g * 8, (void*)&sW[c * 8]);
    }
#pragma unroll
    for (int it = 0; it < 2; ++it) {               // Z: 512 granules (convert)
      int c = t + 256 * it;
      int row = c >> 3, g = (c & 7) ^ (row & 7);
      const float* s = Zsrc + (size_t)row * 256 + k0 + g * 8;
      float4 a0 = *(const float4*)s, a1 = *(const float4*)(s + 4);
      bf16x8 v = {(__bf16)a0.x, (__bf16)a0.y, (__bf16)a0.z, (__bf16)a0.w,
                  (__bf16)a1.x, (__bf16)a1.y, (__bf16)a1.z, (__bf16)a1.w};
      *(bf16x8*)&sZ[c * 8] = v;
    }
    __syncthreads();
#pragma unroll
    for (int ks = 0; ks < 2; ++ks) {
      bf16x8 af[4], bfr[4];
#pragma unroll
      for (int mi = 0; mi < 4; mi++)
        af[mi] = *(const bf16x8*)&sZ[(mi * 16 + fc) * 64 + (((ks * 4 + fr) ^ sw) * 8)];
#pragma unroll
      for (int ni = 0; ni < 4; ni++)
        bfr[ni] = *(const bf16x8*)&sW[(wn + ni * 16 + fc) * 64 + (((ks * 4 + fr) ^ sw) * 8)];
#pragma unroll
      for (int mi = 0; mi < 4; mi++)
#pragma unroll
        for (int ni = 0; ni < 4; ni++)
          acc[mi][ni] = __builtin_amdgcn_mfma_f32_16x16x32_bf16(af[mi], bfr[ni], acc[mi][ni], 0, 0, 0);
    }
  }

  // layer-1 epilogue: bias + elu -> bf16 into sH (granule-xor swizzled rows)
  {
    float bv[4];
#pragma unroll
    for (int ni = 0; ni < 4; ni++) bv[ni] = b1[wn + ni * 16 + fc];
#pragma unroll
    for (int mi = 0; mi < 4; mi++)
#pragma unroll
      for (int ni = 0; ni < 4; ni++) {
        int col = wn + ni * 16 + fc;
        int gc = col >> 3;
#pragma unroll
        for (int r = 0; r < 4; r++) {
          int row = mi * 16 + fr * 4 + r;
          float v = acc[mi][ni][r] + bv[ni];
          v = v > 0.f ? v : (__expf(v) - 1.f);
          int pos = (gc & 24) | ((gc & 7) ^ (row & 7));
          sH[row * 256 + pos * 8 + (col & 7)] = (__bf16)v;
          acc[mi][ni][r] = 0.f;
        }
      }
  }

  // ---- layer 2 (A = sH, resident full-K) ----
  for (int k0 = 0; k0 < 256; k0 += 64) {
    __syncthreads();   // also guarantees: all sH writes done before first read
#pragma unroll
    for (int it = 0; it < 8; ++it) {               // W2: 2048 granules, async DMA
      int c = t + 256 * it;
      int row = c >> 3, g = (c & 7) ^ (row & 7);
      async_copy16(Wb2 + (size_t)row * 256 + k0 + g * 8, (void*)&sW[c * 8]);
    }
    __syncthreads();
    const int kgb = k0 >> 3;
#pragma unroll
    for (int ks = 0; ks < 2; ++ks) {
      bf16x8 af[4], bfr[4];
#pragma unroll
      for (int mi = 0; mi < 4; mi++)
        af[mi] = *(const bf16x8*)&sH[(mi * 16 + fc) * 256 + (kgb + (((ks * 4 + fr) ^ sw))) * 8];
#pragma unroll
      for (int ni = 0; ni < 4; ni++)
        bfr[ni] = *(const bf16x8*)&sW[(wn + ni * 16 + fc) * 64 + (((ks * 4 + fr) ^ sw) * 8)];
#pragma unroll
      for (int mi = 0; mi < 4; mi++)
#pragma unroll
        for (int ni = 0; ni < 4; ni++)
          acc[mi][ni] = __builtin_amdgcn_mfma_f32_16x16x32_bf16(af[mi], bfr[ni], acc[mi][ni], 0, 0, 0);
    }
  }

  // ---- epilogue: bias, cross-wave row-norm, fp8 emit, snorm ----
  float bv[4];
#pragma unroll
  for (int ni = 0; ni < 4; ni++) bv[ni] = b2[wn + ni * 16 + fc];

  __syncthreads();                 // sZ dead; reuse as reduce scratch
  float* red = (float*)sZ;         // [64 rows][4 waves]
  float* red2 = red + 256;

#pragma unroll
  for (int mi = 0; mi < 4; mi++) {
    float ssq[4] = {0.f, 0.f, 0.f, 0.f};
#pragma unroll
    for (int ni = 0; ni < 4; ni++)
#pragma unroll
      for (int r = 0; r < 4; r++) {
        float v = acc[mi][ni][r] + bv[ni];
        acc[mi][ni][r] = v;
        ssq[r] += v * v;
      }
#pragma unroll
    for (int r = 0; r < 4; r++) {
      float v = ssq[r];
#pragma unroll
      for (int off = 1; off < 16; off <<= 1) v += __shfl_xor(v, off, 16);
      if (fc == 0) red[(mi * 16 + fr * 4 + r) * 4 + wave] = v;
    }
  }
  __syncthreads();

#pragma unroll
  for (int mi = 0; mi < 4; mi++) {
    float ssq2[4] = {0.f, 0.f, 0.f, 0.f};
#pragma unroll
    for (int r = 0; r < 4; r++) {
      int row = mi * 16 + fr * 4 + r;
      float ss = red[row * 4] + red[row * 4 + 1] + red[row * 4 + 2] + red[row * 4 + 3];
      float rn = 1.f / fmaxf(sqrtf(ss), 1e-12f);
#pragma unroll
      for (int ni = 0; ni < 4; ni++) {
        float v = acc[mi][ni][r] * rn;
        __hip_fp8_e4m3 q(v);
        Mf8[(size_t)(i0 + row) * 256 + wn + ni * 16 + fc] = q.__x;
        float fv = (float)q;
        ssq2[r] += fv * fv;
      }
    }
#pragma unroll
    for (int r = 0; r < 4; r++) {
      float v = ssq2[r];
#pragma unroll
      for (int off = 1; off < 16; off <<= 1) v += __shfl_xor(v, off, 16);
      if (fc == 0) red2[(mi * 16 + fr * 4 + r) * 4 + wave] = v;
    }
  }
  __syncthreads();
  if (t < 64)
    snorm[i0 + t] = red2[t * 4] + red2[t * 4 + 1] + red2[t * 4 + 2] + red2[t * 4 + 3];
}

// ---------------- symmetric Gram, MX fp8 K=128, fully register-resident ------
// v8: NO LDS, NO BARRIERS. Mf8 (4 MB) is L2-resident; B fragments are read
// per-wave directly from global (L2 ~200cyc, L1-served for the wave pair
// sharing the same wn half) with the same 16B-pair pattern as the A gather.
// Removes: sB8 (64 KB LDS), all tile-loop __syncthreads + vmcnt drains, and
// the staging address math. Residency becomes VGPR-only: <=128 VGPR ->
// 16 waves/CU (4/SIMD), waves fully independent -- attacks the measured ~52%
// barrier/dependency idle at 2 waves/SIMD. L2 traffic ~528 MB (~15 us at L2
// BW): cheap. launch_bounds(256,2) = proven 124-VGPR cap (R5/R7/R11 law:
// cap = 256/arg2; arg2=2 is the known-good point).
__global__ __launch_bounds__(256, 2)
void gram_sym(const u8* __restrict__ Mf8, float* __restrict__ rsum) {
  const int t = threadIdx.x;
  const int lane = t & 63, wave = t >> 6;
  const int wm = (wave >> 1) * 64, wn = (wave & 1) * 64;
  const int fr = lane >> 4, fc = lane & 15;

  // ---- strip mapping (band closed form), long strips dispatched first ----
  int f = 2111 - blockIdx.x;
  int b = 0;
  while (f >= 2 * (b + 1) * (b + 2)) ++b;
  int rem = f - 2 * b * (b + 1);
  int r = rem / (b + 1);
  int q = rem - r * (b + 1);
  int k = 4 * b + 1 + r;
  const int i_t = 128 - k;
  const int jt0 = i_t + 4 * q;
  const int L = min(4, k - 4 * q);
  const int i0 = i_t * 128;

  // gather A fragments into registers (L2/L3-resident; once per strip)
  i32x8 afr[4][2];
  {
    const u8* Ag = Mf8 + (size_t)i0 * 256;
#pragma unroll
    for (int mi = 0; mi < 4; ++mi) {
      const u8* rp = Ag + (size_t)(wm + mi * 16 + fc) * 256 + fr * 32;
#pragma unroll
      for (int kb = 0; kb < 2; ++kb) {
        int4 lo = *(const int4*)(rp + kb * 128);
        int4 hi = *(const int4*)(rp + kb * 128 + 16);
        afr[mi][kb] = (i32x8){lo.x, lo.y, lo.z, lo.w, hi.x, hi.y, hi.z, hi.w};
      }
    }
  }

  float rowacc[4][4];
  float colps[4][4];               // [tile][ni], flushed at strip end
#pragma unroll
  for (int a = 0; a < 4; a++)
#pragma unroll
    for (int rr = 0; rr < 4; rr++) { rowacc[a][rr] = 0.f; colps[a][rr] = 0.f; }

  // per-lane B base within a tile: row (wn + ni*16 + fc), bytes kb*128+fr*32
  const u8* Bbase = Mf8 + (size_t)jt0 * 32768 + (size_t)(wn + fc) * 256 + fr * 32;

#pragma unroll
  for (int jt = 0; jt < 4; ++jt) {
    if (jt < L) {                  // uniform guard (L uniform per block)
      const u8* Bt = Bbase + (size_t)jt * 32768;

      f32x4 acc[4][4];
#pragma unroll
      for (int a = 0; a < 4; a++)
#pragma unroll
        for (int bb = 0; bb < 4; bb++) acc[a][bb] = (f32x4){0.f, 0.f, 0.f, 0.f};

#pragma unroll
      for (int kb = 0; kb < 2; ++kb) {
        i32x8 bfrag[4];
#pragma unroll
        for (int ni = 0; ni < 4; ++ni) {
          const u8* rp = Bt + ni * 4096 + kb * 128;   // ni*16 rows * 256 B
          int4 lo = *(const int4*)rp;
          int4 hi = *(const int4*)(rp + 16);
          bfrag[ni] = (i32x8){lo.x, lo.y, lo.z, lo.w, hi.x, hi.y, hi.z, hi.w};
        }
#pragma unroll
        for (int mi = 0; mi < 4; mi++)
#pragma unroll
          for (int ni = 0; ni < 4; ni++)
            acc[mi][ni] = __builtin_amdgcn_mfma_scale_f32_16x16x128_f8f6f4(
                afr[mi][kb], bfrag[ni], acc[mi][ni], 0, 0, 0, 0x7F, 0, 0x7F);
      }

      // tile epilogue: exp2-folded, register-only accumulation
#pragma unroll
      for (int mi = 0; mi < 4; mi++) {
#pragma unroll
        for (int ni = 0; ni < 4; ni++) {
          float e0 = hw_exp2(acc[mi][ni][0] * EXP2_SCALE);
          float e1 = hw_exp2(acc[mi][ni][1] * EXP2_SCALE);
          float e2 = hw_exp2(acc[mi][ni][2] * EXP2_SCALE);
          float e3 = hw_exp2(acc[mi][ni][3] * EXP2_SCALE);
          rowacc[mi][0] += e0; rowacc[mi][1] += e1;
          rowacc[mi][2] += e2; rowacc[mi][3] += e3;
          colps[jt][ni] += e0 + e1 + e2 + e3;
        }
      }
    }
  }

  // ---- strip-end flush: all global atomics live here ----
  // column partials (skip the diagonal tile: its transpose IS the row sum)
#pragma unroll
  for (int jt = 0; jt < 4; ++jt) {
    if (jt < L) {
      const int j_t = jt0 + jt;
      if (j_t != i_t) {
        const int j0 = j_t * 128;
#pragma unroll
        for (int ni = 0; ni < 4; ni++) {
          float v = colps[jt][ni];
          v += __shfl_xor(v, 16, 64);
          v += __shfl_xor(v, 32, 64);
          if (fr == 0) atomicAdd(&rsum[j0 + wn + ni * 16 + fc], v);
        }
      }
    }
  }

  // row sums: reduce across the 16 fc lanes, one atomic set
#pragma unroll
  for (int mi = 0; mi < 4; mi++) {
#pragma unroll
    for (int rr = 0; rr < 4; rr++) {
      float v = rowacc[mi][rr];
#pragma unroll
      for (int off = 1; off < 16; off <<= 1) v += __shfl_xor(v, off, 16);
      rowacc[mi][rr] = v;
    }
  }
  if (fc == 0) {
#pragma unroll
    for (int mi = 0; mi < 4; mi++) {
      int rbase = i0 + wm + mi * 16 + fr * 4;
      atomicAdd(&rsum[rbase + 0], rowacc[mi][0]);
      atomicAdd(&rsum[rbase + 1], rowacc[mi][1]);
      atomicAdd(&rsum[rbase + 2], rowacc[mi][2]);
      atomicAdd(&rsum[rbase + 3], rowacc[mi][3]);
    }
  }
}

// ---------------- final loss (4 rows / block), fp8 diagonal ------------------
__global__ void final_loss(const u8* __restrict__ Mf8, const float* __restrict__ rsum,
                           const float* __restrict__ snorm, float* __restrict__ out) {
  int i = blockIdx.x * 4 + (threadIdx.x >> 6);
  int lane = threadIdx.x & 63;
  unsigned int ua = ((const unsigned int*)(Mf8 + (size_t)i * 256))[lane];
  unsigned int ub = ((const unsigned int*)(Mf8 + (size_t)(Nn + i) * 256))[lane];
  float d = 0.f;
#pragma unroll
  for (int e = 0; e < 4; ++e) {
    __hip_fp8_e4m3 qa, qb;
    qa.__x = (ua >> (8 * e)) & 0xFF;
    qb.__x = (ub >> (8 * e)) & 0xFF;
    d += (float)qa * (float)qb;
  }
#pragma unroll
  for (int off = 32; off; off >>= 1) d += __shfl_xor(d, off, 64);
  if (lane == 0) {
    float den1 = rsum[i] - __expf(snorm[i] * INV_TAU);
    float den2 = rsum[Nn + i] - __expf(snorm[Nn + i] * INV_TAU);
    out[i] = 0.5f * (logf(den1) + logf(den2)) - d * INV_TAU;
  }
}

extern "C" void kernel_launch(void* const* d_in, const int* in_sizes, int n_in,
                              void* d_out, int out_size, void* d_ws, size_t ws_size,
                              hipStream_t stream) {
  const float* z1 = (const float*)d_in[0];
  const float* z2 = (const float*)d_in[1];
  const float* W1 = (const float*)d_in[2];
  const float* b1 = (const float*)d_in[3];
  const float* W2 = (const float*)d_in[4];
  const float* b2 = (const float*)d_in[5];
  float* out = (float*)d_out;

  char* ws = (char*)d_ws;
  u8*     Mf8   = (u8*)(ws);                           // 4 MB
  float*  rsum  = (float*)(ws + (4u << 20));           // 64 KB
  float*  snorm = (float*)(ws + (4u << 20) + 65536);   // 64 KB
  __bf16* Wb    = (__bf16*)(ws + (4u << 20) + 131072); // 256 KB (bf16 W1|W2)

  // W f32 -> bf16 once
  wcvt<<<64, 256, 0, stream>>>(W1, W2, Wb);

  // fused MLP (both layers) + normalize + fp8 emit + snorm + rsum zeroing
  mlp_norm<<<256, 256, 0, stream>>>(z1, z2, Wb, b1, b2, Mf8, snorm, rsum);

  // upper-triangle strips of <=4 tiles: 2112 blocks, long strips first
  gram_sym<<<2112, 256, 0, stream>>>(Mf8, rsum);

  final_loss<<<Nn / 4, 256, 0, stream>>>(Mf8, rsum, snorm, out);
}

// Round 15
// 166.409 us; speedup vs baseline: 1.9546x; 1.2310x over previous
//
#include <hip/hip_runtime.h>
#include <hip/hip_bf16.h>
#include <hip/hip_fp8.h>
#include <stdint.h>

#define Nn 8192
#define TWO_N 16384
#define INV_TAU 2.0f
// exp(x/TAU) = exp2(x * EXP2_SCALE); we fold sqrt(EXP2_SCALE) into the stored
// fp8 vectors so the Gram epilogue is a bare exp2 (no per-element mul).
#define SQRT_E2S 1.6986436f      /* sqrt(2.885390081777927) */
#define LN2f 0.69314718f

typedef unsigned short u16;
typedef unsigned char u8;
typedef __bf16 bf16x8 __attribute__((ext_vector_type(8)));
typedef float f32x4 __attribute__((ext_vector_type(4)));
typedef int i32x8 __attribute__((ext_vector_type(8)));

typedef const __attribute__((address_space(1))) void* gas_ptr;
typedef __attribute__((address_space(3))) void* las_ptr;

__device__ __forceinline__ void async_copy16(const void* g, void* l) {
  __builtin_amdgcn_global_load_lds((gas_ptr)g, (las_ptr)l, 16, 0, 0);
}

// v_exp_f32: D = 2^S0 (hardware transcendental)
__device__ __forceinline__ float hw_exp2(float x) {
  return __builtin_amdgcn_exp2f(x);
}

// ---------------- W f32 -> bf16 pre-convert (once, ~256 KB out) -------------
__global__ __launch_bounds__(256)
void wcvt(const float* __restrict__ W1, const float* __restrict__ W2,
          __bf16* __restrict__ Wb) {
  int i = (blockIdx.x * 256 + threadIdx.x) * 8;
  const float* s = (i < 65536) ? (W1 + i) : (W2 + (i - 65536));
  float4 a0 = *(const float4*)s, a1 = *(const float4*)(s + 4);
  bf16x8 v = {(__bf16)a0.x, (__bf16)a0.y, (__bf16)a0.z, (__bf16)a0.w,
              (__bf16)a1.x, (__bf16)a1.y, (__bf16)a1.z, (__bf16)a1.w};
  *(bf16x8*)&Wb[i] = v;
}

// ---------------- fused MLP + normalize + SCALED fp8 emit --------------------
// R6 body; ONLY change: the emitted fp8 vector is n * SQRT_E2S (scale folded),
// so dot(m_i,m_j) = EXP2_SCALE * dot(n_i,n_j) and snorm = ||m||^2.
__global__ __launch_bounds__(256)
void mlp_norm(const float* __restrict__ z1, const float* __restrict__ z2,
              const __bf16* __restrict__ Wb, const float* __restrict__ b1,
              const float* __restrict__ b2,
              u8* __restrict__ Mf8, float* __restrict__ snorm,
              float* __restrict__ rsum) {
  __shared__ __bf16 sZ[64 * 64];    // 8 KB  (layer1 A; reduce scratch later)
  __shared__ __bf16 sW[256 * 64];   // 32 KB (W chunk, both layers)
  __shared__ __bf16 sH[64 * 256];   // 32 KB (H1, full K for layer 2)
  const int bx = blockIdx.x;
  const int i0 = bx * 64;
  const float* Zsrc = (bx < 128) ? (z1 + (size_t)i0 * 256)
                                 : (z2 + (size_t)(i0 - Nn) * 256);
  const int t = threadIdx.x;
  const int lane = t & 63, wave = t >> 6;
  const int wn = wave * 64;
  const int fr = lane >> 4, fc = lane & 15;
  const int sw = fc & 7;

  const __bf16* Wb1 = Wb;
  const __bf16* Wb2 = Wb + 65536;

  if (t < 64) rsum[i0 + t] = 0.f;

  f32x4 acc[4][4];
#pragma unroll
  for (int a = 0; a < 4; a++)
#pragma unroll
    for (int b = 0; b < 4; b++) acc[a][b] = (f32x4){0.f, 0.f, 0.f, 0.f};

  // ---- layer 1 ----
  for (int k0 = 0; k0 < 256; k0 += 64) {
    __syncthreads();
#pragma unroll
    for (int it = 0; it < 8; ++it) {               // W1: 2048 granules, async DMA
      int c = t + 256 * it;
      int row = c >> 3, g = (c & 7) ^ (row & 7);
      async_copy16(Wb1 + (size_t)row * 256 + k0 + g * 8, (void*)&sW[c * 8]);
    }
#pragma unroll
    for (int it = 0; it < 2; ++it) {               // Z: 512 granules (convert)
      int c = t + 256 * it;
      int row = c >> 3, g = (c & 7) ^ (row & 7);
      const float* s = Zsrc + (size_t)row * 256 + k0 + g * 8;
      float4 a0 = *(const float4*)s, a1 = *(const float4*)(s + 4);
      bf16x8 v = {(__bf16)a0.x, (__bf16)a0.y, (__bf16)a0.z, (__bf16)a0.w,
                  (__bf16)a1.x, (__bf16)a1.y, (__bf16)a1.z, (__bf16)a1.w};
      *(bf16x8*)&sZ[c * 8] = v;
    }
    __syncthreads();
#pragma unroll
    for (int ks = 0; ks < 2; ++ks) {
      bf16x8 af[4], bfr[4];
#pragma unroll
      for (int mi = 0; mi < 4; mi++)
        af[mi] = *(const bf16x8*)&sZ[(mi * 16 + fc) * 64 + (((ks * 4 + fr) ^ sw) * 8)];
#pragma unroll
      for (int ni = 0; ni < 4; ni++)
        bfr[ni] = *(const bf16x8*)&sW[(wn + ni * 16 + fc) * 64 + (((ks * 4 + fr) ^ sw) * 8)];
#pragma unroll
      for (int mi = 0; mi < 4; mi++)
#pragma unroll
        for (int ni = 0; ni < 4; ni++)
          acc[mi][ni] = __builtin_amdgcn_mfma_f32_16x16x32_bf16(af[mi], bfr[ni], acc[mi][ni], 0, 0, 0);
    }
  }

  // layer-1 epilogue: bias + elu -> bf16 into sH (granule-xor swizzled rows)
  {
    float bv[4];
#pragma unroll
    for (int ni = 0; ni < 4; ni++) bv[ni] = b1[wn + ni * 16 + fc];
#pragma unroll
    for (int mi = 0; mi < 4; mi++)
#pragma unroll
      for (int ni = 0; ni < 4; ni++) {
        int col = wn + ni * 16 + fc;
        int gc = col >> 3;
#pragma unroll
        for (int r = 0; r < 4; r++) {
          int row = mi * 16 + fr * 4 + r;
          float v = acc[mi][ni][r] + bv[ni];
          v = v > 0.f ? v : (__expf(v) - 1.f);
          int pos = (gc & 24) | ((gc & 7) ^ (row & 7));
          sH[row * 256 + pos * 8 + (col & 7)] = (__bf16)v;
          acc[mi][ni][r] = 0.f;
        }
      }
  }

  // ---- layer 2 (A = sH, resident full-K) ----
  for (int k0 = 0; k0 < 256; k0 += 64) {
    __syncthreads();   // also guarantees: all sH writes done before first read
#pragma unroll
    for (int it = 0; it < 8; ++it) {               // W2: 2048 granules, async DMA
      int c = t + 256 * it;
      int row = c >> 3, g = (c & 7) ^ (row & 7);
      async_copy16(Wb2 + (size_t)row * 256 + k0 + g * 8, (void*)&sW[c * 8]);
    }
    __syncthreads();
    const int kgb = k0 >> 3;
#pragma unroll
    for (int ks = 0; ks < 2; ++ks) {
      bf16x8 af[4], bfr[4];
#pragma unroll
      for (int mi = 0; mi < 4; mi++)
        af[mi] = *(const bf16x8*)&sH[(mi * 16 + fc) * 256 + (kgb + (((ks * 4 + fr) ^ sw))) * 8];
#pragma unroll
      for (int ni = 0; ni < 4; ni++)
        bfr[ni] = *(const bf16x8*)&sW[(wn + ni * 16 + fc) * 64 + (((ks * 4 + fr) ^ sw) * 8)];
#pragma unroll
      for (int mi = 0; mi < 4; mi++)
#pragma unroll
        for (int ni = 0; ni < 4; ni++)
          acc[mi][ni] = __builtin_amdgcn_mfma_f32_16x16x32_bf16(af[mi], bfr[ni], acc[mi][ni], 0, 0, 0);
    }
  }

  // ---- epilogue: bias, cross-wave row-norm, SCALED fp8 emit, snorm ----
  float bv[4];
#pragma unroll
  for (int ni = 0; ni < 4; ni++) bv[ni] = b2[wn + ni * 16 + fc];

  __syncthreads();                 // sZ dead; reuse as reduce scratch
  float* red = (float*)sZ;         // [64 rows][4 waves]
  float* red2 = red + 256;

#pragma unroll
  for (int mi = 0; mi < 4; mi++) {
    float ssq[4] = {0.f, 0.f, 0.f, 0.f};
#pragma unroll
    for (int ni = 0; ni < 4; ni++)
#pragma unroll
      for (int r = 0; r < 4; r++) {
        float v = acc[mi][ni][r] + bv[ni];
        acc[mi][ni][r] = v;
        ssq[r] += v * v;
      }
#pragma unroll
    for (int r = 0; r < 4; r++) {
      float v = ssq[r];
#pragma unroll
      for (int off = 1; off < 16; off <<= 1) v += __shfl_xor(v, off, 16);
      if (fc == 0) red[(mi * 16 + fr * 4 + r) * 4 + wave] = v;
    }
  }
  __syncthreads();

#pragma unroll
  for (int mi = 0; mi < 4; mi++) {
    float ssq2[4] = {0.f, 0.f, 0.f, 0.f};
#pragma unroll
    for (int r = 0; r < 4; r++) {
      int row = mi * 16 + fr * 4 + r;
      float ss = red[row * 4] + red[row * 4 + 1] + red[row * 4 + 2] + red[row * 4 + 3];
      float rn = SQRT_E2S / fmaxf(sqrtf(ss), 1e-12f);   // scale folded here
#pragma unroll
      for (int ni = 0; ni < 4; ni++) {
        float v = acc[mi][ni][r] * rn;
        __hip_fp8_e4m3 q(v);
        Mf8[(size_t)(i0 + row) * 256 + wn + ni * 16 + fc] = q.__x;
        float fv = (float)q;
        ssq2[r] += fv * fv;                              // snorm = ||m||^2
      }
    }
#pragma unroll
    for (int r = 0; r < 4; r++) {
      float v = ssq2[r];
#pragma unroll
      for (int off = 1; off < 16; off <<= 1) v += __shfl_xor(v, off, 16);
      if (fc == 0) red2[(mi * 16 + fr * 4 + r) * 4 + wave] = v;
    }
  }
  __syncthreads();
  if (t < 64)
    snorm[i0 + t] = red2[t * 4] + red2[t * 4 + 1] + red2[t * 4 + 2] + red2[t * 4 + 3];
}

// ---------------- symmetric Gram, MX fp8 K=128, A-in-regs, B dbuf ------------
// v9: R6 dbuf structure + R12's intra-wave MFMA||VALU interleave (proven
// 1.34x per-wave) + scale-folded epilogue (bare exp2, no mul) +
// __launch_bounds__(256,2) forcing VGPR<=124 so 2 blocks/CU residency is
// KEPT (R12's only failure mode: 132 VGPR -> 1 block/CU). ~8 cold regs may
// spill -- watch WRITE_SIZE; R5/R11 spills were 40-60 hot regs, not 8.
__global__ __launch_bounds__(256, 2)
void gram_sym(const u8* __restrict__ Mf8, float* __restrict__ rsum) {
  __shared__ u8 sB8[2][128 * 256];   // 2 x 32 KB
  const int t = threadIdx.x;
  const int lane = t & 63, wave = t >> 6;
  const int wm = (wave >> 1) * 64, wn = (wave & 1) * 64;
  const int fr = lane >> 4, fc = lane & 15;

  // ---- strip mapping (band closed form), long strips dispatched first ----
  int f = 2111 - blockIdx.x;
  int b = 0;
  while (f >= 2 * (b + 1) * (b + 2)) ++b;
  int rem = f - 2 * b * (b + 1);
  int r = rem / (b + 1);
  int q = rem - r * (b + 1);
  int k = 4 * b + 1 + r;
  const int i_t = 128 - k;
  const int jt0 = i_t + 4 * q;
  const int L = min(4, k - 4 * q);
  const int i0 = i_t * 128;

  // stage B(tile 0) into buffer 0
  {
    const u8* Bg = Mf8 + (size_t)jt0 * 128 * 256;
#pragma unroll
    for (int it = 0; it < 8; ++it) {
      int c = t + 256 * it;
      int row = c >> 4, slot = c & 15;
      int g = slot ^ (row & 15);
      async_copy16(Bg + (size_t)row * 256 + g * 16, (void*)&sB8[0][c * 16]);
    }
  }

  // gather A fragments into registers (L2/L3-resident; once per strip)
  i32x8 afr[4][2];
  {
    const u8* Ag = Mf8 + (size_t)i0 * 256;
#pragma unroll
    for (int mi = 0; mi < 4; ++mi) {
      const u8* rp = Ag + (size_t)(wm + mi * 16 + fc) * 256 + fr * 32;
#pragma unroll
      for (int kb = 0; kb < 2; ++kb) {
        int4 lo = *(const int4*)(rp + kb * 128);
        int4 hi = *(const int4*)(rp + kb * 128 + 16);
        afr[mi][kb] = (i32x8){lo.x, lo.y, lo.z, lo.w, hi.x, hi.y, hi.z, hi.w};
      }
    }
  }

  float rowacc[4][4];
  float colps[4][4];               // [tile][ni], flushed at strip end
  f32x4 acc[4][4];                 // persists across tiles; re-zeroed in EPI
#pragma unroll
  for (int a = 0; a < 4; a++)
#pragma unroll
    for (int rr = 0; rr < 4; rr++) {
      rowacc[a][rr] = 0.f; colps[a][rr] = 0.f;
      acc[a][rr] = (f32x4){0.f, 0.f, 0.f, 0.f};
    }

  // epilogue for one mi group: bare exp2 (scale pre-folded into fp8 data) +
  // row/col accumulate + acc re-zero. Interleaved between kb1 MFMA groups.
#define EPI(m_, jt_)                                                      \
  {                                                                       \
    _Pragma("unroll")                                                     \
    for (int ni_ = 0; ni_ < 4; ++ni_) {                                   \
      float e0 = hw_exp2(acc[m_][ni_][0]);                                \
      float e1 = hw_exp2(acc[m_][ni_][1]);                                \
      float e2 = hw_exp2(acc[m_][ni_][2]);                                \
      float e3 = hw_exp2(acc[m_][ni_][3]);                                \
      rowacc[m_][0] += e0; rowacc[m_][1] += e1;                           \
      rowacc[m_][2] += e2; rowacc[m_][3] += e3;                           \
      colps[jt_][ni_] += e0 + e1 + e2 + e3;                               \
      acc[m_][ni_] = (f32x4){0.f, 0.f, 0.f, 0.f};                         \
    }                                                                     \
  }

#pragma unroll
  for (int jt = 0; jt < 4; ++jt) {
    if (jt < L) {                  // block-uniform guard (L uniform)
      const int j_t = jt0 + jt;
      const u8* sB = &sB8[jt & 1][0];

      __syncthreads();   // drains B(jt) staging (issued >=1 tile ago; landed)

      if (jt + 1 < L) {  // prefetch B(jt+1) behind the barrier
        const u8* Bg = Mf8 + (size_t)(j_t + 1) * 128 * 256;
        u8* dst = &sB8[(jt + 1) & 1][0];
#pragma unroll
        for (int it = 0; it < 8; ++it) {
          int c = t + 256 * it;
          int row = c >> 4, slot = c & 15;
          int g = slot ^ (row & 15);
          async_copy16(Bg + (size_t)row * 256 + g * 16, (void*)&dst[c * 16]);
        }
      }

      // ---- kb = 0: read frags, issue all 16 MFMA ----
      i32x8 b0[4];
#pragma unroll
      for (int ni = 0; ni < 4; ++ni) {
        const u8* base = sB + (wn + ni * 16 + fc) * 256;
        int g0 = fr * 2;
        int4 lo = *(const int4*)(base + ((g0 ^ fc) * 16));
        int4 hi = *(const int4*)(base + (((g0 + 1) ^ fc) * 16));
        b0[ni] = (i32x8){lo.x, lo.y, lo.z, lo.w, hi.x, hi.y, hi.z, hi.w};
      }
#pragma unroll
      for (int mi = 0; mi < 4; mi++)
#pragma unroll
        for (int ni = 0; ni < 4; ni++)
          acc[mi][ni] = __builtin_amdgcn_mfma_scale_f32_16x16x128_f8f6f4(
              afr[mi][0], b0[ni], acc[mi][ni], 0, 0, 0, 0x7F, 0, 0x7F);

      // ---- kb = 1 frags ----
      i32x8 b1[4];
#pragma unroll
      for (int ni = 0; ni < 4; ++ni) {
        const u8* base = sB + (wn + ni * 16 + fc) * 256;
        int g0 = 8 + fr * 2;
        int4 lo = *(const int4*)(base + ((g0 ^ fc) * 16));
        int4 hi = *(const int4*)(base + (((g0 + 1) ^ fc) * 16));
        b1[ni] = (i32x8){lo.x, lo.y, lo.z, lo.w, hi.x, hi.y, hi.z, hi.w};
      }

      // ---- kb = 1: per-mi groups with interleaved epilogue ----
#pragma unroll
      for (int ni = 0; ni < 4; ni++)
        acc[0][ni] = __builtin_amdgcn_mfma_scale_f32_16x16x128_f8f6f4(
            afr[0][1], b1[ni], acc[0][ni], 0, 0, 0, 0x7F, 0, 0x7F);
#pragma unroll
      for (int ni = 0; ni < 4; ni++)
        acc[1][ni] = __builtin_amdgcn_mfma_scale_f32_16x16x128_f8f6f4(
            afr[1][1], b1[ni], acc[1][ni], 0, 0, 0, 0x7F, 0, 0x7F);
      EPI(0, jt)
#pragma unroll
      for (int ni = 0; ni < 4; ni++)
        acc[2][ni] = __builtin_amdgcn_mfma_scale_f32_16x16x128_f8f6f4(
            afr[2][1], b1[ni], acc[2][ni], 0, 0, 0, 0x7F, 0, 0x7F);
      EPI(1, jt)
#pragma unroll
      for (int ni = 0; ni < 4; ni++)
        acc[3][ni] = __builtin_amdgcn_mfma_scale_f32_16x16x128_f8f6f4(
            afr[3][1], b1[ni], acc[3][ni], 0, 0, 0, 0x7F, 0, 0x7F);
      EPI(2, jt)
      EPI(3, jt)
    }
  }
#undef EPI

  // ---- strip-end flush: all global atomics live here, no barrier after ----
  // column partials (skip the diagonal tile: its transpose IS the row sum)
#pragma unroll
  for (int jt = 0; jt < 4; ++jt) {
    if (jt < L) {
      const int j_t = jt0 + jt;
      if (j_t != i_t) {
        const int j0 = j_t * 128;
#pragma unroll
        for (int ni = 0; ni < 4; ni++) {
          float v = colps[jt][ni];
          v += __shfl_xor(v, 16, 64);
          v += __shfl_xor(v, 32, 64);
          if (fr == 0) atomicAdd(&rsum[j0 + wn + ni * 16 + fc], v);
        }
      }
    }
  }

  // row sums: reduce across the 16 fc lanes, one atomic set
#pragma unroll
  for (int mi = 0; mi < 4; mi++) {
#pragma unroll
    for (int rr = 0; rr < 4; rr++) {
      float v = rowacc[mi][rr];
#pragma unroll
      for (int off = 1; off < 16; off <<= 1) v += __shfl_xor(v, off, 16);
      rowacc[mi][rr] = v;
    }
  }
  if (fc == 0) {
#pragma unroll
    for (int mi = 0; mi < 4; mi++) {
      int rbase = i0 + wm + mi * 16 + fr * 4;
      atomicAdd(&rsum[rbase + 0], rowacc[mi][0]);
      atomicAdd(&rsum[rbase + 1], rowacc[mi][1]);
      atomicAdd(&rsum[rbase + 2], rowacc[mi][2]);
      atomicAdd(&rsum[rbase + 3], rowacc[mi][3]);
    }
  }
}

// ---------------- final loss (4 rows / block), scaled-fp8 diagonal -----------
// With the folded scale: f = exp2(dot_m); self-term = exp2(snorm);
// log f12 = dot_m * ln2.
__global__ void final_loss(const u8* __restrict__ Mf8, const float* __restrict__ rsum,
                           const float* __restrict__ snorm, float* __restrict__ out) {
  int i = blockIdx.x * 4 + (threadIdx.x >> 6);
  int lane = threadIdx.x & 63;
  unsigned int ua = ((const unsigned int*)(Mf8 + (size_t)i * 256))[lane];
  unsigned int ub = ((const unsigned int*)(Mf8 + (size_t)(Nn + i) * 256))[lane];
  float d = 0.f;
#pragma unroll
  for (int e = 0; e < 4; ++e) {
    __hip_fp8_e4m3 qa, qb;
    qa.__x = (ua >> (8 * e)) & 0xFF;
    qb.__x = (ub >> (8 * e)) & 0xFF;
    d += (float)qa * (float)qb;
  }
#pragma unroll
  for (int off = 32; off; off >>= 1) d += __shfl_xor(d, off, 64);
  if (lane == 0) {
    float den1 = rsum[i] - hw_exp2(snorm[i]);
    float den2 = rsum[Nn + i] - hw_exp2(snorm[Nn + i]);
    out[i] = 0.5f * (logf(den1) + logf(den2)) - d * LN2f;
  }
}

extern "C" void kernel_launch(void* const* d_in, const int* in_sizes, int n_in,
                              void* d_out, int out_size, void* d_ws, size_t ws_size,
                              hipStream_t stream) {
  const float* z1 = (const float*)d_in[0];
  const float* z2 = (const float*)d_in[1];
  const float* W1 = (const float*)d_in[2];
  const float* b1 = (const float*)d_in[3];
  const float* W2 = (const float*)d_in[4];
  const float* b2 = (const float*)d_in[5];
  float* out = (float*)d_out;

  char* ws = (char*)d_ws;
  u8*     Mf8   = (u8*)(ws);                           // 4 MB
  float*  rsum  = (float*)(ws + (4u << 20));           // 64 KB
  float*  snorm = (float*)(ws + (4u << 20) + 65536);   // 64 KB
  __bf16* Wb    = (__bf16*)(ws + (4u << 20) + 131072); // 256 KB (bf16 W1|W2)

  // W f32 -> bf16 once
  wcvt<<<64, 256, 0, stream>>>(W1, W2, Wb);

  // fused MLP (both layers) + normalize + scaled fp8 emit + snorm + rsum zero
  mlp_norm<<<256, 256, 0, stream>>>(z1, z2, Wb, b1, b2, Mf8, snorm, rsum);

  // upper-triangle strips of <=4 tiles: 2112 blocks, long strips first
  gram_sym<<<2112, 256, 0, stream>>>(Mf8, rsum);

  final_loss<<<Nn / 4, 256, 0, stream>>>(Mf8, rsum, snorm, out);
}